// Round 1
// baseline (359.290 us; speedup 1.0000x reference)
//
#include <hip/hip_runtime.h>
#include <math.h>

#define NBINS 4096
#define CAP   4096
#define MAXC  300
#define TOPN  100

// ---------------- pass 1: per-ROI score + validity + histogram ----------------
__global__ __launch_bounds__(256)
void rcnn_pass1(const float* __restrict__ cls, const float* __restrict__ bbox,
                const float* __restrict__ rois, const float* __restrict__ iminfo,
                float* __restrict__ scores, unsigned int* __restrict__ hist, int N)
{
    int i = blockIdx.x * blockDim.x + threadIdx.x;
    if (i >= N) return;

    float p0 = cls[5*i+0];
    float p1 = cls[5*i+1];
    float p2 = cls[5*i+2];
    float p3 = cls[5*i+3];
    float p4 = cls[5*i+4];
    float m = p1; int a = 1;
    if (p2 > m) { m = p2; a = 2; }
    if (p3 > m) { m = p3; a = 3; }
    if (p4 > m) { m = p4; a = 4; }

    float score = -1.0f;
    if (((1.0f - p0) >= 0.2f) && (m > 0.1f)) {
        float x1 = rois[5*i+1], y1 = rois[5*i+2], x2 = rois[5*i+3], y2 = rois[5*i+4];
        float w  = x2 - x1 + 1.0f;
        float h  = y2 - y1 + 1.0f;
        float cx = x1 + 0.5f*(w - 1.0f);
        float cy = y1 + 0.5f*(h - 1.0f);
        const float* d = bbox + 20*i + 4*a;
        float d0 = d[0]*0.1f, d1 = d[1]*0.1f, d2 = d[2]*0.2f, d3 = d[3]*0.2f;
        float pcx = d0*w + cx;
        float pcy = d1*h + cy;
        float pw  = expf(d2)*w;
        float ph  = expf(d3)*h;
        float Himg = iminfo[0], Wimg = iminfo[1];
        float bx1 = fminf(fmaxf(pcx - 0.5f*(pw-1.0f), 0.0f), Wimg-1.0f);
        float by1 = fminf(fmaxf(pcy - 0.5f*(ph-1.0f), 0.0f), Himg-1.0f);
        float bx2 = fminf(fmaxf(pcx + 0.5f*(pw-1.0f), 0.0f), Wimg-1.0f);
        float by2 = fminf(fmaxf(pcy + 0.5f*(ph-1.0f), 0.0f), Himg-1.0f);
        float bw = bx2 - bx1 + 1.0f;
        float bh = by2 - by1 + 1.0f;
        if ((bw >= 6.0f) || (bh >= 6.0f)) score = m;
    }
    scores[i] = score;
    if (score > -0.5f) {
        int bin = (int)(score * (float)NBINS);
        bin = bin > NBINS-1 ? NBINS-1 : bin;
        atomicAdd(&hist[bin], 1u);
    }
}

// ---------------- pass 2: find threshold bin tau (largest with suffix>=300) ----------------
__global__ __launch_bounds__(1024)
void rcnn_pass2(const unsigned int* __restrict__ hist, int* __restrict__ taubin)
{
    __shared__ unsigned int suf[1024];
    __shared__ int g_sh;
    int t = threadIdx.x;
    unsigned int v = hist[4*t] + hist[4*t+1] + hist[4*t+2] + hist[4*t+3];
    suf[t] = v;
    __syncthreads();
    // Hillis-Steele suffix sum over 1024 coarse groups
    for (int d = 1; d < 1024; d <<= 1) {
        unsigned int add = (t + d < 1024) ? suf[t + d] : 0u;
        __syncthreads();
        suf[t] += add;
        __syncthreads();
    }
    if (t == 0) g_sh = -1;
    __syncthreads();
    if (suf[t] >= MAXC && (t == 1023 || suf[t+1] < MAXC)) g_sh = t;  // unique (monotone)
    __syncthreads();
    if (t == 0) {
        int g = g_sh;
        int tau = 0;  // fewer than 300 valid -> take everything
        if (g >= 0) {
            unsigned int cum = (g == 1023) ? 0u : suf[g+1];
            tau = 4*g;
            for (int k = 3; k >= 0; k--) {
                cum += hist[4*g + k];
                if (cum >= MAXC) { tau = 4*g + k; break; }
            }
        }
        *taubin = tau;
    }
}

// ---------------- pass 3: compact candidates above threshold ----------------
__global__ __launch_bounds__(256)
void rcnn_pass3(const float* __restrict__ scores, const int* __restrict__ taubin,
                float* __restrict__ cscore, int* __restrict__ cidx,
                unsigned int* __restrict__ counter, int N)
{
    int i = blockIdx.x * blockDim.x + threadIdx.x;
    if (i >= N) return;
    float s = scores[i];
    if (s > -0.5f) {
        int bin = (int)(s * (float)NBINS);
        bin = bin > NBINS-1 ? NBINS-1 : bin;
        if (bin >= *taubin) {
            unsigned int pos = atomicAdd(counter, 1u);
            if (pos < CAP) { cscore[pos] = s; cidx[pos] = i; }
        }
    }
}

// ---------------- final: stable rank sort -> decode -> NMS -> write top-100 ----------------
__global__ __launch_bounds__(256)
void rcnn_final(const float* __restrict__ cls, const float* __restrict__ bbox,
                const float* __restrict__ rois, const float* __restrict__ iminfo,
                const float* __restrict__ cscore, const int* __restrict__ cidx,
                const unsigned int* __restrict__ counter, float* __restrict__ out)
{
    __shared__ float s_s[CAP];
    __shared__ int   s_id[CAP];
    __shared__ float ts[MAXC];
    __shared__ int   tid_[MAXC];
    __shared__ float bx_[MAXC][4];
    __shared__ float pr_[MAXC][5];
    __shared__ int   keep[MAXC];
    __shared__ float orows[TOPN*10];
    int t = threadIdx.x;
    int M = (int)*counter; if (M > CAP) M = CAP;

    for (int i = t; i < M; i += 256) { s_s[i] = cscore[i]; s_id[i] = cidx[i]; }
    for (int r = t; r < MAXC; r += 256) { ts[r] = -1.0f; tid_[r] = -1; keep[r] = 0; }
    for (int k = t; k < TOPN*10; k += 256) orows[k] = 0.0f;
    __syncthreads();

    // exact stable rank: (score desc, index asc) == jax.lax.top_k order
    for (int i = t; i < M; i += 256) {
        float si = s_s[i]; int di = s_id[i];
        int r = 0;
        for (int j = 0; j < M; j++) {
            float sj = s_s[j];
            int   dj = s_id[j];
            r += (sj > si) || (sj == si && dj < di);
        }
        if (r < MAXC) { ts[r] = si; tid_[r] = di; }
    }
    __syncthreads();

    // decode boxes + gather probs for the ranked 300
    float Himg = iminfo[0], Wimg = iminfo[1];
    for (int r = t; r < MAXC; r += 256) {
        int i = tid_[r];
        if (i >= 0) {
            float p0 = cls[5*i+0], p1 = cls[5*i+1], p2 = cls[5*i+2], p3 = cls[5*i+3], p4 = cls[5*i+4];
            pr_[r][0]=p0; pr_[r][1]=p1; pr_[r][2]=p2; pr_[r][3]=p3; pr_[r][4]=p4;
            float m = p1; int a = 1;
            if (p2 > m) { m = p2; a = 2; }
            if (p3 > m) { m = p3; a = 3; }
            if (p4 > m) { m = p4; a = 4; }
            float x1 = rois[5*i+1], y1 = rois[5*i+2], x2 = rois[5*i+3], y2 = rois[5*i+4];
            float w  = x2 - x1 + 1.0f, h = y2 - y1 + 1.0f;
            float cx = x1 + 0.5f*(w-1.0f), cy = y1 + 0.5f*(h-1.0f);
            const float* d = bbox + 20*i + 4*a;
            float d0 = d[0]*0.1f, d1 = d[1]*0.1f, d2 = d[2]*0.2f, d3 = d[3]*0.2f;
            float pcx = d0*w + cx, pcy = d1*h + cy;
            float pw  = expf(d2)*w, ph = expf(d3)*h;
            bx_[r][0] = fminf(fmaxf(pcx - 0.5f*(pw-1.0f), 0.0f), Wimg-1.0f);
            bx_[r][1] = fminf(fmaxf(pcy - 0.5f*(ph-1.0f), 0.0f), Himg-1.0f);
            bx_[r][2] = fminf(fmaxf(pcx + 0.5f*(pw-1.0f), 0.0f), Wimg-1.0f);
            bx_[r][3] = fminf(fmaxf(pcy + 0.5f*(ph-1.0f), 0.0f), Himg-1.0f);
            keep[r] = 1;
        }
    }
    __syncthreads();

    // sequential NMS, IoU on the fly (0/0 -> NaN -> no suppress, matches JAX)
    for (int i = 0; i < MAXC; i++) {
        if (keep[i]) {
            float ax1 = bx_[i][0], ay1 = bx_[i][1], ax2 = bx_[i][2], ay2 = bx_[i][3];
            float areaA = (ax2-ax1)*(ay2-ay1);
            for (int j = i+1+t; j < MAXC; j += 256) {
                if (keep[j]) {
                    float bx1 = bx_[j][0], by1 = bx_[j][1], bx2 = bx_[j][2], by2 = bx_[j][3];
                    float lx = fmaxf(ax1, bx1), ly = fmaxf(ay1, by1);
                    float rx = fminf(ax2, bx2), ry = fminf(ay2, by2);
                    float iw = fmaxf(rx-lx, 0.0f), ih = fmaxf(ry-ly, 0.0f);
                    float inter = iw*ih;
                    float areaB = (bx2-bx1)*(by2-by1);
                    float iou = inter / (areaA + areaB - inter);
                    if (iou > 0.5f) keep[j] = 0;
                }
            }
        }
        __syncthreads();
    }

    // prefix-count -> slots -> rows
    for (int r = t; r < MAXC; r += 256) {
        if (keep[r]) {
            int ord = 0;
            for (int q = 0; q < r; q++) ord += keep[q];
            if (ord < TOPN) {
                float* row = &orows[ord*10];
                row[0] = 0.0f;
                row[1] = bx_[r][0]; row[2] = bx_[r][1]; row[3] = bx_[r][2]; row[4] = bx_[r][3];
                row[5] = pr_[r][0]; row[6] = pr_[r][1]; row[7] = pr_[r][2]; row[8] = pr_[r][3]; row[9] = pr_[r][4];
            }
        }
    }
    __syncthreads();
    for (int k = t; k < TOPN*10; k += 256) out[k] = orows[k];
}

extern "C" void kernel_launch(void* const* d_in, const int* in_sizes, int n_in,
                              void* d_out, int out_size, void* d_ws, size_t ws_size,
                              hipStream_t stream)
{
    const float* cls    = (const float*)d_in[0];
    const float* bbox   = (const float*)d_in[1];
    const float* rois   = (const float*)d_in[2];
    const float* iminfo = (const float*)d_in[3];
    int N = in_sizes[0] / 5;

    char* ws = (char*)d_ws;
    float* scores = (float*)ws;
    size_t off = ((size_t)N * 4 + 255) & ~(size_t)255;
    unsigned int* hist    = (unsigned int*)(ws + off); off += NBINS * 4;
    int*          taubin  = (int*)(ws + off);          off += 256;
    unsigned int* counter = (unsigned int*)(ws + off); off += 256;
    float*        cscore  = (float*)(ws + off);        off += CAP * 4;
    int*          cidx    = (int*)(ws + off);          off += CAP * 4;

    hipMemsetAsync(hist, 0, NBINS * 4, stream);
    hipMemsetAsync(counter, 0, 4, stream);

    int blocks = (N + 255) / 256;
    rcnn_pass1<<<blocks, 256, 0, stream>>>(cls, bbox, rois, iminfo, scores, hist, N);
    rcnn_pass2<<<1, 1024, 0, stream>>>(hist, taubin);
    rcnn_pass3<<<blocks, 256, 0, stream>>>(scores, taubin, cscore, cidx, counter, N);
    rcnn_final<<<1, 256, 0, stream>>>(cls, bbox, rois, iminfo, cscore, cidx, counter, (float*)d_out);
}

// Round 2
// 302.155 us; speedup vs baseline: 1.1891x; 1.1891x over previous
//
#include <hip/hip_runtime.h>
#include <math.h>

#define NBINS 4096
#define CAP   4096
#define MAXC  300
#define MAXCP 320
#define TOPN  100

// Shared box-decode; expression-identical to round-1 (absmax was 0.0).
__device__ __forceinline__ void decode4(float x1, float y1, float x2, float y2,
                                        float4 d4, float Wimg, float Himg,
                                        float& bx1, float& by1, float& bx2, float& by2)
{
    float w  = x2 - x1 + 1.0f;
    float h  = y2 - y1 + 1.0f;
    float cx = x1 + 0.5f*(w - 1.0f);
    float cy = y1 + 0.5f*(h - 1.0f);
    float d0 = d4.x*0.1f, d1 = d4.y*0.1f, d2 = d4.z*0.2f, d3 = d4.w*0.2f;
    float pcx = d0*w + cx;
    float pcy = d1*h + cy;
    float pw  = expf(d2)*w;
    float ph  = expf(d3)*h;
    bx1 = fminf(fmaxf(pcx - 0.5f*(pw-1.0f), 0.0f), Wimg-1.0f);
    by1 = fminf(fmaxf(pcy - 0.5f*(ph-1.0f), 0.0f), Himg-1.0f);
    bx2 = fminf(fmaxf(pcx + 0.5f*(pw-1.0f), 0.0f), Wimg-1.0f);
    by2 = fminf(fmaxf(pcy + 0.5f*(ph-1.0f), 0.0f), Himg-1.0f);
}

// ---------------- pass 1: 4 ROIs/thread, float4 loads, score + histogram ----------------
__global__ __launch_bounds__(256)
void rcnn_pass1(const float4* __restrict__ cls4, const float4* __restrict__ bbox4,
                const float4* __restrict__ rois4, const float* __restrict__ iminfo,
                float4* __restrict__ scores4, unsigned int* __restrict__ hist, int Ng)
{
    int g = blockIdx.x * blockDim.x + threadIdx.x;
    if (g >= Ng) return;

    float c[20], q[20];
    #pragma unroll
    for (int v = 0; v < 5; v++) {
        float4 cv = cls4[5*g + v];
        c[4*v] = cv.x; c[4*v+1] = cv.y; c[4*v+2] = cv.z; c[4*v+3] = cv.w;
        float4 rv = rois4[5*g + v];
        q[4*v] = rv.x; q[4*v+1] = rv.y; q[4*v+2] = rv.z; q[4*v+3] = rv.w;
    }
    float Himg = iminfo[0], Wimg = iminfo[1];

    float s[4];
    #pragma unroll
    for (int j = 0; j < 4; j++) {
        float p0 = c[5*j], p1 = c[5*j+1], p2 = c[5*j+2], p3 = c[5*j+3], p4 = c[5*j+4];
        float m = p1; int a = 1;
        if (p2 > m) { m = p2; a = 2; }
        if (p3 > m) { m = p3; a = 3; }
        if (p4 > m) { m = p4; a = 4; }
        float sc = -1.0f;
        if (((1.0f - p0) >= 0.2f) && (m > 0.1f)) {
            float4 d4 = bbox4[20*g + 5*j + a];
            float bx1, by1, bx2, by2;
            decode4(q[5*j+1], q[5*j+2], q[5*j+3], q[5*j+4], d4, Wimg, Himg, bx1, by1, bx2, by2);
            float bw = bx2 - bx1 + 1.0f;
            float bh = by2 - by1 + 1.0f;
            if ((bw >= 6.0f) || (bh >= 6.0f)) sc = m;
        }
        s[j] = sc;
    }
    scores4[g] = make_float4(s[0], s[1], s[2], s[3]);
    #pragma unroll
    for (int j = 0; j < 4; j++) {
        if (s[j] > -0.5f) {
            int bin = (int)(s[j] * (float)NBINS);
            bin = bin > NBINS-1 ? NBINS-1 : bin;
            atomicAdd(&hist[bin], 1u);
        }
    }
}

// ---------------- pass 2: threshold bin tau (largest with suffix >= 300) ----------------
__global__ __launch_bounds__(1024)
void rcnn_pass2(const unsigned int* __restrict__ hist, int* __restrict__ taubin)
{
    __shared__ unsigned int suf[1024];
    __shared__ int g_sh;
    int t = threadIdx.x;
    unsigned int v = hist[4*t] + hist[4*t+1] + hist[4*t+2] + hist[4*t+3];
    suf[t] = v;
    __syncthreads();
    for (int d = 1; d < 1024; d <<= 1) {
        unsigned int add = (t + d < 1024) ? suf[t + d] : 0u;
        __syncthreads();
        suf[t] += add;
        __syncthreads();
    }
    if (t == 0) g_sh = -1;
    __syncthreads();
    if (suf[t] >= MAXC && (t == 1023 || suf[t+1] < MAXC)) g_sh = t;
    __syncthreads();
    if (t == 0) {
        int g = g_sh;
        int tau = 0;
        if (g >= 0) {
            unsigned int cum = (g == 1023) ? 0u : suf[g+1];
            tau = 4*g;
            for (int k = 3; k >= 0; k--) {
                cum += hist[4*g + k];
                if (cum >= MAXC) { tau = 4*g + k; break; }
            }
        }
        *taubin = tau;
    }
}

// ---------------- pass 3: compact candidates above threshold (float4 reads) ----------------
__global__ __launch_bounds__(256)
void rcnn_pass3(const float4* __restrict__ scores4, const int* __restrict__ taubin,
                float* __restrict__ cscore, int* __restrict__ cidx,
                unsigned int* __restrict__ counter, int Ng)
{
    int g = blockIdx.x * blockDim.x + threadIdx.x;
    if (g >= Ng) return;
    float4 s4 = scores4[g];
    int tau = *taubin;
    float ss[4] = { s4.x, s4.y, s4.z, s4.w };
    #pragma unroll
    for (int j = 0; j < 4; j++) {
        float s = ss[j];
        if (s > -0.5f) {
            int bin = (int)(s * (float)NBINS);
            bin = bin > NBINS-1 ? NBINS-1 : bin;
            if (bin >= tau) {
                unsigned int pos = atomicAdd(counter, 1u);
                if (pos < CAP) { cscore[pos] = s; cidx[pos] = 4*g + j; }
            }
        }
    }
}

// ---------------- final: rank sort -> decode -> bitmask NMS -> write top-100 ----------------
__global__ __launch_bounds__(1024)
void rcnn_final(const float* __restrict__ cls, const float* __restrict__ bbox,
                const float* __restrict__ rois, const float* __restrict__ iminfo,
                const float* __restrict__ cscore, const int* __restrict__ cidx,
                const unsigned int* __restrict__ counter, float* __restrict__ out)
{
    __shared__ float s_s[CAP];
    __shared__ int   s_id[CAP];
    __shared__ float ts[MAXC];
    __shared__ int   tid_[MAXC];
    __shared__ float bx_[MAXCP][4];
    __shared__ float pr_[MAXC][5];
    __shared__ unsigned long long sup[MAXC][5];
    __shared__ unsigned long long maskw[5];
    __shared__ float orows[TOPN*10];
    const int t  = threadIdx.x;
    const int NT = 1024;
    int M = (int)*counter; if (M > CAP) M = CAP;

    for (int i = t; i < M; i += NT)  { s_s[i] = cscore[i]; s_id[i] = cidx[i]; }
    for (int r = t; r < MAXC; r += NT) { ts[r] = -1.0f; tid_[r] = -1; }
    for (int r = t; r < MAXCP; r += NT) { bx_[r][0]=0.0f; bx_[r][1]=0.0f; bx_[r][2]=0.0f; bx_[r][3]=0.0f; }
    if (t < 5) maskw[t] = 0ull;
    for (int k = t; k < TOPN*10; k += NT) orows[k] = 0.0f;
    __syncthreads();

    // exact stable rank: (score desc, index asc) == jax.lax.top_k order
    for (int i = t; i < M; i += NT) {
        float si = s_s[i]; int di = s_id[i];
        int r = 0;
        for (int j = 0; j < M; j++) {
            float sj = s_s[j];
            int   dj = s_id[j];
            r += (sj > si) || (sj == si && dj < di);
        }
        if (r < MAXC) { ts[r] = si; tid_[r] = di; }
    }
    __syncthreads();

    // decode boxes + gather probs for the ranked 300; build validity mask
    float Himg = iminfo[0], Wimg = iminfo[1];
    for (int r = t; r < MAXC; r += NT) {
        int i = tid_[r];
        if (i >= 0) {
            float p0 = cls[5*i], p1 = cls[5*i+1], p2 = cls[5*i+2], p3 = cls[5*i+3], p4 = cls[5*i+4];
            pr_[r][0]=p0; pr_[r][1]=p1; pr_[r][2]=p2; pr_[r][3]=p3; pr_[r][4]=p4;
            float m = p1; int a = 1;
            if (p2 > m) { m = p2; a = 2; }
            if (p3 > m) { m = p3; a = 3; }
            if (p4 > m) { m = p4; a = 4; }
            float4 d4 = ((const float4*)bbox)[5*i + a];
            float bx1, by1, bx2, by2;
            decode4(rois[5*i+1], rois[5*i+2], rois[5*i+3], rois[5*i+4], d4, Wimg, Himg, bx1, by1, bx2, by2);
            bx_[r][0]=bx1; bx_[r][1]=by1; bx_[r][2]=bx2; bx_[r][3]=by2;
            atomicOr(&maskw[r>>6], 1ull << (r & 63));
        }
    }
    __syncthreads();

    // parallel suppression bitmask matrix: sup[i][w] bit b = (j=64w+b suppressible by i)
    for (int task = t; task < MAXC*5; task += NT) {
        int w = task / MAXC;
        int i = task - w*MAXC;
        unsigned long long bits = 0ull;
        int j0 = w << 6;
        if (j0 + 63 > i) {  // word contains some j > i
            float ax1 = bx_[i][0], ay1 = bx_[i][1], ax2 = bx_[i][2], ay2 = bx_[i][3];
            float areaA = (ax2-ax1)*(ay2-ay1);
            for (int b = 0; b < 64; b++) {
                int j = j0 + b;
                float b1 = bx_[j][0], b2 = bx_[j][1], b3 = bx_[j][2], b4 = bx_[j][3];
                float lx = fmaxf(ax1, b1), ly = fmaxf(ay1, b2);
                float rx = fminf(ax2, b3), ry = fminf(ay2, b4);
                float iw = fmaxf(rx - lx, 0.0f), ih = fmaxf(ry - ly, 0.0f);
                float inter = iw * ih;
                float areaB = (b3 - b1) * (b4 - b2);
                float iou = inter / (areaA + areaB - inter);  // NaN/neg-safe: compare false
                bits |= (iou > 0.5f) ? (1ull << b) : 0ull;
            }
            unsigned long long jgt = (i < j0) ? ~0ull
                                  : ((i - j0) >= 63 ? 0ull : ~((1ull << (i - j0 + 1)) - 1ull));
            bits &= jgt & maskw[w];
        }
        sup[i][w] = bits;
    }
    __syncthreads();

    // serial bit-scan (loop-carried dep = 5 reg ANDs; LDS reads unconditional -> pipelined)
    if (t == 0) {
        unsigned long long kw[5];
        #pragma unroll
        for (int qq = 0; qq < 5; qq++) kw[qq] = maskw[qq];
        #pragma unroll
        for (int w2 = 0; w2 < 5; w2++) {
            int nb = (w2 == 4) ? (MAXC - 4*64) : 64;
            for (int b = 0; b < nb; b++) {
                int i = (w2 << 6) + b;
                unsigned long long m = ((kw[w2] >> b) & 1ull) ? ~0ull : 0ull;
                kw[0] &= ~(sup[i][0] & m);
                kw[1] &= ~(sup[i][1] & m);
                kw[2] &= ~(sup[i][2] & m);
                kw[3] &= ~(sup[i][3] & m);
                kw[4] &= ~(sup[i][4] & m);
            }
        }
        #pragma unroll
        for (int qq = 0; qq < 5; qq++) maskw[qq] = kw[qq];
    }
    __syncthreads();

    // popcount-prefix -> output slots
    for (int r = t; r < MAXC; r += NT) {
        if ((maskw[r>>6] >> (r & 63)) & 1ull) {
            int ord = 0;
            for (int w2 = 0; w2 < (r >> 6); w2++) ord += __popcll(maskw[w2]);
            ord += __popcll(maskw[r>>6] & ((1ull << (r & 63)) - 1ull));
            if (ord < TOPN) {
                float* row = &orows[ord*10];
                row[0] = 0.0f;
                row[1] = bx_[r][0]; row[2] = bx_[r][1]; row[3] = bx_[r][2]; row[4] = bx_[r][3];
                row[5] = pr_[r][0]; row[6] = pr_[r][1]; row[7] = pr_[r][2]; row[8] = pr_[r][3]; row[9] = pr_[r][4];
            }
        }
    }
    __syncthreads();
    for (int k = t; k < TOPN*10; k += NT) out[k] = orows[k];
}

extern "C" void kernel_launch(void* const* d_in, const int* in_sizes, int n_in,
                              void* d_out, int out_size, void* d_ws, size_t ws_size,
                              hipStream_t stream)
{
    const float* cls    = (const float*)d_in[0];
    const float* bbox   = (const float*)d_in[1];
    const float* rois   = (const float*)d_in[2];
    const float* iminfo = (const float*)d_in[3];
    int N  = in_sizes[0] / 5;
    int Ng = N / 4;  // N = 1e6, divisible by 4

    char* ws = (char*)d_ws;
    float* scores = (float*)ws;
    size_t off = ((size_t)N * 4 + 255) & ~(size_t)255;
    unsigned int* hist    = (unsigned int*)(ws + off); off += NBINS * 4;
    int*          taubin  = (int*)(ws + off);          off += 256;
    unsigned int* counter = (unsigned int*)(ws + off); off += 256;
    float*        cscore  = (float*)(ws + off);        off += CAP * 4;
    int*          cidx    = (int*)(ws + off);          off += CAP * 4;

    hipMemsetAsync(hist, 0, NBINS * 4, stream);
    hipMemsetAsync(counter, 0, 4, stream);

    int blocksG = (Ng + 255) / 256;
    rcnn_pass1<<<blocksG, 256, 0, stream>>>((const float4*)cls, (const float4*)bbox,
                                            (const float4*)rois, iminfo,
                                            (float4*)scores, hist, Ng);
    rcnn_pass2<<<1, 1024, 0, stream>>>(hist, taubin);
    rcnn_pass3<<<blocksG, 256, 0, stream>>>((const float4*)scores, taubin,
                                            cscore, cidx, counter, Ng);
    rcnn_final<<<1, 1024, 0, stream>>>(cls, bbox, rois, iminfo,
                                       cscore, cidx, counter, (float*)d_out);
}

// Round 3
// 220.351 us; speedup vs baseline: 1.6305x; 1.3712x over previous
//
#include <hip/hip_runtime.h>
#include <math.h>

#define NBINS 4096
#define CAP   4096
#define MAXC  300
#define MAXCP 320
#define TOPN  100

// Shared box-decode; expression-identical to round-1/2 (absmax was 0.0).
__device__ __forceinline__ void decode4(float x1, float y1, float x2, float y2,
                                        float4 d4, float Wimg, float Himg,
                                        float& bx1, float& by1, float& bx2, float& by2)
{
    float w  = x2 - x1 + 1.0f;
    float h  = y2 - y1 + 1.0f;
    float cx = x1 + 0.5f*(w - 1.0f);
    float cy = y1 + 0.5f*(h - 1.0f);
    float d0 = d4.x*0.1f, d1 = d4.y*0.1f, d2 = d4.z*0.2f, d3 = d4.w*0.2f;
    float pcx = d0*w + cx;
    float pcy = d1*h + cy;
    float pw  = expf(d2)*w;
    float ph  = expf(d3)*h;
    bx1 = fminf(fmaxf(pcx - 0.5f*(pw-1.0f), 0.0f), Wimg-1.0f);
    by1 = fminf(fmaxf(pcy - 0.5f*(ph-1.0f), 0.0f), Himg-1.0f);
    bx2 = fminf(fmaxf(pcx + 0.5f*(pw-1.0f), 0.0f), Wimg-1.0f);
    by2 = fminf(fmaxf(pcy + 0.5f*(ph-1.0f), 0.0f), Himg-1.0f);
}

// ---------------- pass 1: 4 ROIs/thread, float4 loads, scores only (NO atomics) ----------------
__global__ __launch_bounds__(256)
void rcnn_pass1(const float4* __restrict__ cls4, const float4* __restrict__ bbox4,
                const float4* __restrict__ rois4, const float* __restrict__ iminfo,
                float4* __restrict__ scores4,
                unsigned int* __restrict__ hist, unsigned int* __restrict__ counter, int Ng)
{
    // block 0 zero-inits hist + counter (replaces two hipMemsetAsync dispatches);
    // safe: hist/counter are only touched by later kernels (after this one completes).
    if (blockIdx.x == 0) {
        for (int k = threadIdx.x; k < NBINS; k += 256) hist[k] = 0u;
        if (threadIdx.x == 0) *counter = 0u;
    }

    int g = blockIdx.x * blockDim.x + threadIdx.x;
    if (g >= Ng) return;

    float c[20], q[20];
    #pragma unroll
    for (int v = 0; v < 5; v++) {
        float4 cv = cls4[5*g + v];
        c[4*v] = cv.x; c[4*v+1] = cv.y; c[4*v+2] = cv.z; c[4*v+3] = cv.w;
        float4 rv = rois4[5*g + v];
        q[4*v] = rv.x; q[4*v+1] = rv.y; q[4*v+2] = rv.z; q[4*v+3] = rv.w;
    }
    float Himg = iminfo[0], Wimg = iminfo[1];

    float s[4];
    #pragma unroll
    for (int j = 0; j < 4; j++) {
        float p0 = c[5*j], p1 = c[5*j+1], p2 = c[5*j+2], p3 = c[5*j+3], p4 = c[5*j+4];
        float m = p1; int a = 1;
        if (p2 > m) { m = p2; a = 2; }
        if (p3 > m) { m = p3; a = 3; }
        if (p4 > m) { m = p4; a = 4; }
        float sc = -1.0f;
        if (((1.0f - p0) >= 0.2f) && (m > 0.1f)) {
            float4 d4 = bbox4[20*g + 5*j + a];
            float bx1, by1, bx2, by2;
            decode4(q[5*j+1], q[5*j+2], q[5*j+3], q[5*j+4], d4, Wimg, Himg, bx1, by1, bx2, by2);
            float bw = bx2 - bx1 + 1.0f;
            float bh = by2 - by1 + 1.0f;
            if ((bw >= 6.0f) || (bh >= 6.0f)) sc = m;
        }
        s[j] = sc;
    }
    scores4[g] = make_float4(s[0], s[1], s[2], s[3]);
}

// ---------------- pass 1b: LDS histogram over scores (few blocks, coalesced flush) ----------------
__global__ __launch_bounds__(1024)
void rcnn_hist(const float4* __restrict__ scores4, unsigned int* __restrict__ hist, int Ng)
{
    __shared__ unsigned int lh[NBINS];
    const int t = threadIdx.x;
    for (int k = t; k < NBINS; k += 1024) lh[k] = 0u;
    __syncthreads();

    int stride = gridDim.x * 1024;
    for (int g = blockIdx.x * 1024 + t; g < Ng; g += stride) {
        float4 s4 = scores4[g];
        float ss[4] = { s4.x, s4.y, s4.z, s4.w };
        #pragma unroll
        for (int j = 0; j < 4; j++) {
            float s = ss[j];
            if (s > -0.5f) {
                int bin = (int)(s * (float)NBINS);
                bin = bin > NBINS-1 ? NBINS-1 : bin;
                atomicAdd(&lh[bin], 1u);
            }
        }
    }
    __syncthreads();
    for (int k = t; k < NBINS; k += 1024) {
        unsigned int v = lh[k];
        if (v) atomicAdd(&hist[k], v);
    }
}

// ---------------- pass 2: threshold bin tau (largest with suffix >= 300) ----------------
__global__ __launch_bounds__(1024)
void rcnn_pass2(const unsigned int* __restrict__ hist, int* __restrict__ taubin)
{
    __shared__ unsigned int suf[1024];
    __shared__ int g_sh;
    int t = threadIdx.x;
    unsigned int v = hist[4*t] + hist[4*t+1] + hist[4*t+2] + hist[4*t+3];
    suf[t] = v;
    __syncthreads();
    for (int d = 1; d < 1024; d <<= 1) {
        unsigned int add = (t + d < 1024) ? suf[t + d] : 0u;
        __syncthreads();
        suf[t] += add;
        __syncthreads();
    }
    if (t == 0) g_sh = -1;
    __syncthreads();
    if (suf[t] >= MAXC && (t == 1023 || suf[t+1] < MAXC)) g_sh = t;
    __syncthreads();
    if (t == 0) {
        int g = g_sh;
        int tau = 0;
        if (g >= 0) {
            unsigned int cum = (g == 1023) ? 0u : suf[g+1];
            tau = 4*g;
            for (int k = 3; k >= 0; k--) {
                cum += hist[4*g + k];
                if (cum >= MAXC) { tau = 4*g + k; break; }
            }
        }
        *taubin = tau;
    }
}

// ---------------- pass 3: compact candidates above threshold (float4 reads) ----------------
__global__ __launch_bounds__(256)
void rcnn_pass3(const float4* __restrict__ scores4, const int* __restrict__ taubin,
                float* __restrict__ cscore, int* __restrict__ cidx,
                unsigned int* __restrict__ counter, int Ng)
{
    int g = blockIdx.x * blockDim.x + threadIdx.x;
    if (g >= Ng) return;
    float4 s4 = scores4[g];
    int tau = *taubin;
    float ss[4] = { s4.x, s4.y, s4.z, s4.w };
    #pragma unroll
    for (int j = 0; j < 4; j++) {
        float s = ss[j];
        if (s > -0.5f) {
            int bin = (int)(s * (float)NBINS);
            bin = bin > NBINS-1 ? NBINS-1 : bin;
            if (bin >= tau) {
                unsigned int pos = atomicAdd(counter, 1u);
                if (pos < CAP) { cscore[pos] = s; cidx[pos] = 4*g + j; }
            }
        }
    }
}

// ---------------- final: rank sort -> decode -> bitmask NMS -> write top-100 ----------------
__global__ __launch_bounds__(1024)
void rcnn_final(const float* __restrict__ cls, const float* __restrict__ bbox,
                const float* __restrict__ rois, const float* __restrict__ iminfo,
                const float* __restrict__ cscore, const int* __restrict__ cidx,
                const unsigned int* __restrict__ counter, float* __restrict__ out)
{
    __shared__ float s_s[CAP];
    __shared__ int   s_id[CAP];
    __shared__ float ts[MAXC];
    __shared__ int   tid_[MAXC];
    __shared__ float bx_[MAXCP][4];
    __shared__ float pr_[MAXC][5];
    __shared__ unsigned long long sup[MAXC][5];
    __shared__ unsigned long long maskw[5];
    __shared__ float orows[TOPN*10];
    const int t  = threadIdx.x;
    const int NT = 1024;
    int M = (int)*counter; if (M > CAP) M = CAP;

    for (int i = t; i < M; i += NT)  { s_s[i] = cscore[i]; s_id[i] = cidx[i]; }
    for (int r = t; r < MAXC; r += NT) { ts[r] = -1.0f; tid_[r] = -1; }
    for (int r = t; r < MAXCP; r += NT) { bx_[r][0]=0.0f; bx_[r][1]=0.0f; bx_[r][2]=0.0f; bx_[r][3]=0.0f; }
    if (t < 5) maskw[t] = 0ull;
    for (int k = t; k < TOPN*10; k += NT) orows[k] = 0.0f;
    __syncthreads();

    // exact stable rank: (score desc, index asc) == jax.lax.top_k order
    for (int i = t; i < M; i += NT) {
        float si = s_s[i]; int di = s_id[i];
        int r = 0;
        for (int j = 0; j < M; j++) {
            float sj = s_s[j];
            int   dj = s_id[j];
            r += (sj > si) || (sj == si && dj < di);
        }
        if (r < MAXC) { ts[r] = si; tid_[r] = di; }
    }
    __syncthreads();

    // decode boxes + gather probs for the ranked 300; build validity mask
    float Himg = iminfo[0], Wimg = iminfo[1];
    for (int r = t; r < MAXC; r += NT) {
        int i = tid_[r];
        if (i >= 0) {
            float p0 = cls[5*i], p1 = cls[5*i+1], p2 = cls[5*i+2], p3 = cls[5*i+3], p4 = cls[5*i+4];
            pr_[r][0]=p0; pr_[r][1]=p1; pr_[r][2]=p2; pr_[r][3]=p3; pr_[r][4]=p4;
            float m = p1; int a = 1;
            if (p2 > m) { m = p2; a = 2; }
            if (p3 > m) { m = p3; a = 3; }
            if (p4 > m) { m = p4; a = 4; }
            float4 d4 = ((const float4*)bbox)[5*i + a];
            float bx1, by1, bx2, by2;
            decode4(rois[5*i+1], rois[5*i+2], rois[5*i+3], rois[5*i+4], d4, Wimg, Himg, bx1, by1, bx2, by2);
            bx_[r][0]=bx1; bx_[r][1]=by1; bx_[r][2]=bx2; bx_[r][3]=by2;
            atomicOr(&maskw[r>>6], 1ull << (r & 63));
        }
    }
    __syncthreads();

    // parallel suppression bitmask matrix: sup[i][w] bit b = (j=64w+b suppressible by i)
    for (int task = t; task < MAXC*5; task += NT) {
        int w = task / MAXC;
        int i = task - w*MAXC;
        unsigned long long bits = 0ull;
        int j0 = w << 6;
        if (j0 + 63 > i) {
            float ax1 = bx_[i][0], ay1 = bx_[i][1], ax2 = bx_[i][2], ay2 = bx_[i][3];
            float areaA = (ax2-ax1)*(ay2-ay1);
            for (int b = 0; b < 64; b++) {
                int j = j0 + b;
                float b1 = bx_[j][0], b2 = bx_[j][1], b3 = bx_[j][2], b4 = bx_[j][3];
                float lx = fmaxf(ax1, b1), ly = fmaxf(ay1, b2);
                float rx = fminf(ax2, b3), ry = fminf(ay2, b4);
                float iw = fmaxf(rx - lx, 0.0f), ih = fmaxf(ry - ly, 0.0f);
                float inter = iw * ih;
                float areaB = (b3 - b1) * (b4 - b2);
                float iou = inter / (areaA + areaB - inter);  // NaN/neg-safe: compare false
                bits |= (iou > 0.5f) ? (1ull << b) : 0ull;
            }
            unsigned long long jgt = (i < j0) ? ~0ull
                                  : ((i - j0) >= 63 ? 0ull : ~((1ull << (i - j0 + 1)) - 1ull));
            bits &= jgt & maskw[w];
        }
        sup[i][w] = bits;
    }
    __syncthreads();

    // serial bit-scan (loop-carried dep = 5 reg ANDs)
    if (t == 0) {
        unsigned long long kw[5];
        #pragma unroll
        for (int qq = 0; qq < 5; qq++) kw[qq] = maskw[qq];
        #pragma unroll
        for (int w2 = 0; w2 < 5; w2++) {
            int nb = (w2 == 4) ? (MAXC - 4*64) : 64;
            for (int b = 0; b < nb; b++) {
                int i = (w2 << 6) + b;
                unsigned long long m = ((kw[w2] >> b) & 1ull) ? ~0ull : 0ull;
                kw[0] &= ~(sup[i][0] & m);
                kw[1] &= ~(sup[i][1] & m);
                kw[2] &= ~(sup[i][2] & m);
                kw[3] &= ~(sup[i][3] & m);
                kw[4] &= ~(sup[i][4] & m);
            }
        }
        #pragma unroll
        for (int qq = 0; qq < 5; qq++) maskw[qq] = kw[qq];
    }
    __syncthreads();

    // popcount-prefix -> output slots
    for (int r = t; r < MAXC; r += NT) {
        if ((maskw[r>>6] >> (r & 63)) & 1ull) {
            int ord = 0;
            for (int w2 = 0; w2 < (r >> 6); w2++) ord += __popcll(maskw[w2]);
            ord += __popcll(maskw[r>>6] & ((1ull << (r & 63)) - 1ull));
            if (ord < TOPN) {
                float* row = &orows[ord*10];
                row[0] = 0.0f;
                row[1] = bx_[r][0]; row[2] = bx_[r][1]; row[3] = bx_[r][2]; row[4] = bx_[r][3];
                row[5] = pr_[r][0]; row[6] = pr_[r][1]; row[7] = pr_[r][2]; row[8] = pr_[r][3]; row[9] = pr_[r][4];
            }
        }
    }
    __syncthreads();
    for (int k = t; k < TOPN*10; k += NT) out[k] = orows[k];
}

extern "C" void kernel_launch(void* const* d_in, const int* in_sizes, int n_in,
                              void* d_out, int out_size, void* d_ws, size_t ws_size,
                              hipStream_t stream)
{
    const float* cls    = (const float*)d_in[0];
    const float* bbox   = (const float*)d_in[1];
    const float* rois   = (const float*)d_in[2];
    const float* iminfo = (const float*)d_in[3];
    int N  = in_sizes[0] / 5;
    int Ng = N / 4;  // N = 1e6, divisible by 4

    char* ws = (char*)d_ws;
    float* scores = (float*)ws;
    size_t off = ((size_t)N * 4 + 255) & ~(size_t)255;
    unsigned int* hist    = (unsigned int*)(ws + off); off += NBINS * 4;
    int*          taubin  = (int*)(ws + off);          off += 256;
    unsigned int* counter = (unsigned int*)(ws + off); off += 256;
    float*        cscore  = (float*)(ws + off);        off += CAP * 4;
    int*          cidx    = (int*)(ws + off);          off += CAP * 4;

    int blocksG = (Ng + 255) / 256;
    rcnn_pass1<<<blocksG, 256, 0, stream>>>((const float4*)cls, (const float4*)bbox,
                                            (const float4*)rois, iminfo,
                                            (float4*)scores, hist, counter, Ng);
    rcnn_hist<<<64, 1024, 0, stream>>>((const float4*)scores, hist, Ng);
    rcnn_pass2<<<1, 1024, 0, stream>>>(hist, taubin);
    rcnn_pass3<<<blocksG, 256, 0, stream>>>((const float4*)scores, taubin,
                                            cscore, cidx, counter, Ng);
    rcnn_final<<<1, 1024, 0, stream>>>(cls, bbox, rois, iminfo,
                                       cscore, cidx, counter, (float*)d_out);
}